// Round 6
// baseline (451.026 us; speedup 1.0000x reference)
//
#include <hip/hip_runtime.h>
#include <hip/hip_fp16.h>
#include <cmath>

#define H 128
#define GAMMA 0.1f
#define EPS 0.1f
#define NEG 0.01f
#define NGRAPH 256

typedef _Float16 half_t;
typedef _Float16 f16x8 __attribute__((ext_vector_type(8)));
typedef _Float16 f16x4 __attribute__((ext_vector_type(4)));
typedef float f32x4 __attribute__((ext_vector_type(4)));

__device__ __forceinline__ float fast_tanh(float v) {
    float e = __builtin_amdgcn_exp2f(v * 2.8853900817779268f);
    float r = __builtin_amdgcn_rcpf(e + 1.0f);
    return 1.0f - 2.0f * r;
}

// ---------------- precompute combined transposed weights, f16
__global__ void prep_kernel(const float* __restrict__ W, const float* __restrict__ lin_w,
                            half_t* __restrict__ WtT) {
    int idx = blockIdx.x * 256 + threadIdx.x;   // 32768 threads
    int j = idx >> 8, k = idx & 255;
    float v;
    if (k < H) v = W[j * H + k] - W[k * H + j] - (j == k ? GAMMA : 0.f);
    else       v = lin_w[j * H + (k - H)];
    WtT[j * 256 + k] = (half_t)v;
}

// ---------------- f32 -> f16 cast (x0 -> xh)
__global__ void cast_kernel(const float* __restrict__ x, half_t* __restrict__ xh, int n4) {
    int i = blockIdx.x * 256 + threadIdx.x;
    if (i < n4) {
        float4 v = *(const float4*)(x + (size_t)i * 4);
        half_t* o = xh + (size_t)i * 4;
        o[0] = (half_t)v.x; o[1] = (half_t)v.y; o[2] = (half_t)v.z; o[3] = (half_t)v.w;
    }
}

// ---------------- CSR build
__global__ void count_kernel(const int* __restrict__ dst, int* __restrict__ deg, int E) {
    int e = blockIdx.x * blockDim.x + threadIdx.x;
    if (e < E) atomicAdd(&deg[dst[e]], 1);
}

#define SCHUNK 2048
__global__ __launch_bounds__(256) void scan_part(const int* __restrict__ deg,
                                                 int* __restrict__ partials, int N) {
    __shared__ int red[256];
    int t = threadIdx.x, b = blockIdx.x;
    int base = b * SCHUNK + t * 8;
    int s = 0;
#pragma unroll
    for (int i = 0; i < 8; ++i) { int idx = base + i; if (idx < N) s += deg[idx]; }
    red[t] = s;
    __syncthreads();
    for (int off = 128; off > 0; off >>= 1) {
        if (t < off) red[t] += red[t + off];
        __syncthreads();
    }
    if (t == 0) partials[b] = red[0];
}

__global__ void scan_mid(const int* __restrict__ partials, int* __restrict__ blkoff, int nblk) {
    int lane = threadIdx.x;   // 64 threads
    int p = (lane < nblk) ? partials[lane] : 0;
    int v = p;
    for (int off = 1; off < 64; off <<= 1) {
        int u = __shfl_up(v, off);
        if (lane >= off) v += u;
    }
    if (lane < nblk) blkoff[lane] = v - p;
}

__global__ __launch_bounds__(256) void scan_final(const int* __restrict__ deg,
        const int* __restrict__ blkoff, int* __restrict__ row_start,
        int* __restrict__ cursor, int N, int E) {
    __shared__ int red[256];
    int t = threadIdx.x, b = blockIdx.x;
    int base = b * SCHUNK + t * 8;
    int v[8]; int s = 0;
#pragma unroll
    for (int i = 0; i < 8; ++i) { int idx = base + i; v[i] = (idx < N) ? deg[idx] : 0; s += v[i]; }
    red[t] = s;
    __syncthreads();
    for (int off = 1; off < 256; off <<= 1) {
        int u = (t >= off) ? red[t - off] : 0;
        __syncthreads();
        red[t] += u;
        __syncthreads();
    }
    int run = blkoff[b] + red[t] - s;
#pragma unroll
    for (int i = 0; i < 8; ++i) {
        int idx = base + i;
        if (idx < N) { row_start[idx] = run; cursor[idx] = run; run += v[i]; }
    }
    if (b == 0 && t == 0) row_start[N] = E;
}

__global__ void fill_kernel(const int* __restrict__ src, const int* __restrict__ dst,
                            int* __restrict__ cursor, int* __restrict__ csr_src, int E) {
    int e = blockIdx.x * blockDim.x + threadIdx.x;
    if (e < E) {
        int p = atomicAdd(&cursor[dst[e]], 1);
        csr_src[p] = src[e];
    }
}

// ---------------- gather aggregation: one wave per dst, 4 rows per load step.
// lane = 16*quad + li ; lane covers features [8*li, 8*li+8) (f16x8 = 16B).
// quad q takes edge j+q; combined via shfl_xor(16),(32) at the end.
// NOTE: ds_bpermute (__shfl) from an exec-inactive lane is UNDEFINED on CDNA.
// The remainder path must keep ALL lanes active for the shfl (uniform branch),
// guarding only the accumulate. (R5 bug: shfl inside `if (quad < rem)`.)
__global__ __launch_bounds__(256) void gather_agg(const half_t* __restrict__ xh,
        const int* __restrict__ row_start, const int* __restrict__ csr_src,
        half_t* __restrict__ xaggh, int N) {
    int node = blockIdx.x * 4 + (threadIdx.x >> 6);
    if (node >= N) return;
    int lane = threadIdx.x & 63;
    int quad = lane >> 4, li = lane & 15;
    int begin = row_start[node], end = row_start[node + 1];
    float acc[8] = {0.f, 0.f, 0.f, 0.f, 0.f, 0.f, 0.f, 0.f};
    for (int base = begin; base < end; base += 64) {
        int cnt = min(64, end - base);
        int myidx = (lane < cnt) ? csr_src[base + lane] : 0;
        int j = 0;
        for (; j + 3 < cnt; j += 4) {           // uniform: all 64 lanes shfl
            int s0 = __shfl(myidx, j + quad);
            f16x8 v = *(const f16x8*)(xh + (size_t)s0 * H + li * 8);
#pragma unroll
            for (int k = 0; k < 8; ++k) acc[k] += (float)v[k];
        }
        int rem = cnt - j;                      // 0..3, wave-uniform
        if (rem > 0) {                          // uniform branch: all lanes active
            int sel = j + (quad < rem ? quad : 0);   // idle quads read a valid lane
            int s0 = __shfl(myidx, sel);             // all lanes push -> defined
            f16x8 v = *(const f16x8*)(xh + (size_t)s0 * H + li * 8);
            if (quad < rem) {
#pragma unroll
                for (int k = 0; k < 8; ++k) acc[k] += (float)v[k];
            }
        }
    }
#pragma unroll
    for (int k = 0; k < 8; ++k) {
        acc[k] += __shfl_xor(acc[k], 16);
        acc[k] += __shfl_xor(acc[k], 32);
    }
    if (quad == 0) {
        f16x8 o;
#pragma unroll
        for (int k = 0; k < 8; ++k) o[k] = (half_t)acc[k];
        *(f16x8*)(xaggh + (size_t)node * H + li * 8) = o;
    }
}

// ---------------- fused conv+update via f16 MFMA
#define CROWS 128
#define BLDW 264   // 256 + 8 halfs pad
__global__ __launch_bounds__(256) void conv_mfma(
        const float* __restrict__ xin, const half_t* __restrict__ xh,
        const half_t* __restrict__ xaggh, const half_t* __restrict__ WtT,
        const float* __restrict__ bias,
        float* __restrict__ xout, half_t* __restrict__ xouth, int N, int write_h) {
    __shared__ __align__(16) half_t sB[128 * BLDW];
    int tid = threadIdx.x;
    for (int c = tid; c < 4096; c += 256) {
        int j = c >> 5, off = (c & 31) * 8;
        *(f16x8*)&sB[j * BLDW + off] = *(const f16x8*)(WtT + j * 256 + off);
    }
    __syncthreads();

    int wave = tid >> 6, lane = tid & 63;
    int q = lane >> 4, m = lane & 15;
    int rowbase = blockIdx.x * CROWS + wave * 32;

    f32x4 acc[2][8];
#pragma unroll
    for (int rt = 0; rt < 2; ++rt)
#pragma unroll
        for (int ct = 0; ct < 8; ++ct) acc[rt][ct] = (f32x4){0.f, 0.f, 0.f, 0.f};

#pragma unroll
    for (int s = 0; s < 8; ++s) {
        const half_t* srcA = (s < 4) ? xh : xaggh;
        int koff = (s & 3) * 32 + q * 8;
        f16x8 afrag[2];
#pragma unroll
        for (int rt = 0; rt < 2; ++rt) {
            int row = rowbase + rt * 16 + m;
            row = min(row, N - 1);
            afrag[rt] = *(const f16x8*)(srcA + (size_t)row * H + koff);
        }
#pragma unroll
        for (int ct = 0; ct < 8; ++ct) {
            f16x8 bfrag = *(const f16x8*)&sB[(ct * 16 + m) * BLDW + s * 32 + q * 8];
            acc[0][ct] = __builtin_amdgcn_mfma_f32_16x16x32_f16(afrag[0], bfrag, acc[0][ct], 0, 0, 0);
            acc[1][ct] = __builtin_amdgcn_mfma_f32_16x16x32_f16(afrag[1], bfrag, acc[1][ct], 0, 0, 0);
        }
    }

#pragma unroll
    for (int rt = 0; rt < 2; ++rt) {
#pragma unroll
        for (int r = 0; r < 4; ++r) {
            int row = rowbase + rt * 16 + q * 4 + r;
            if (row < N) {
#pragma unroll
                for (int ct = 0; ct < 8; ++ct) {
                    int col = ct * 16 + m;
                    float c = acc[rt][ct][r] + bias[col];
                    float o = xin[(size_t)row * H + col] + EPS * fast_tanh(c);
                    xout[(size_t)row * H + col] = o;
                    if (write_h) xouth[(size_t)row * H + col] = (half_t)o;
                }
            }
        }
    }
}

// ---------------- triple pooling: 1 block/graph, 1024 thr = 8 row-slots
__global__ __launch_bounds__(1024) void pool_kernel(const float* __restrict__ x,
        const int* __restrict__ batch, float* __restrict__ pooled, int N) {
    __shared__ float ssum[8][128];
    __shared__ float smax[8][128];
    int g = blockIdx.x, t = threadIdx.x;
    int feat = t & 127, slot = t >> 7;   // 8 slots
    int lo = 0, hi = N;
    while (lo < hi) { int mid = (lo + hi) >> 1; if (batch[mid] < g) lo = mid + 1; else hi = mid; }
    int start = lo;
    hi = N;
    while (lo < hi) { int mid = (lo + hi) >> 1; if (batch[mid] < g + 1) lo = mid + 1; else hi = mid; }
    int end = lo;
    float sum = 0.f, mx = -INFINITY;
    for (int n = start + slot; n < end; n += 8) {
        float v = x[(size_t)n * H + feat];
        sum += v;
        mx = fmaxf(mx, v);
    }
    ssum[slot][feat] = sum;
    smax[slot][feat] = mx;
    __syncthreads();
    if (t < 128) {
        float s = 0.f, m = -INFINITY;
#pragma unroll
        for (int k = 0; k < 8; ++k) { s += ssum[k][t]; m = fmaxf(m, smax[k][t]); }
        int cnt = end - start;
        pooled[g * 384 + t] = s;
        pooled[g * 384 + 128 + t] = (cnt > 0) ? m : 0.f;
        pooled[g * 384 + 256 + t] = s / (float)(cnt > 0 ? cnt : 1);
    }
}

// ---------------- final 2-layer MLP with leaky relu
__global__ void mlp_kernel(const float* __restrict__ pooled, const float* __restrict__ l1_w,
                           const float* __restrict__ l1_b, const float* __restrict__ l2_w,
                           const float* __restrict__ l2_b, float* __restrict__ out) {
    __shared__ __align__(16) float sp[384];
    __shared__ __align__(16) float sh[192];
    int g = blockIdx.x, tid = threadIdx.x;  // 256 threads
    for (int i = tid; i < 384; i += 256) sp[i] = pooled[g * 384 + i];
    __syncthreads();
    if (tid < 192) {
        float acc = l1_b[tid];
        const float* wr = l1_w + (size_t)tid * 384;
        for (int k = 0; k < 384; k += 4) {
            float4 w = *(const float4*)(wr + k);
            float4 p = *(const float4*)(sp + k);
            acc += w.x * p.x + w.y * p.y + w.z * p.z + w.w * p.w;
        }
        sh[tid] = acc > 0.f ? acc : NEG * acc;
    }
    __syncthreads();
    if (tid < 64) {
        float acc = l2_b[tid];
        const float* wr = l2_w + (size_t)tid * 192;
        for (int k = 0; k < 192; k += 4) {
            float4 w = *(const float4*)(wr + k);
            float4 p = *(const float4*)(sh + k);
            acc += w.x * p.x + w.y * p.y + w.z * p.z + w.w * p.w;
        }
        out[g * 64 + tid] = acc > 0.f ? acc : NEG * acc;
    }
}

extern "C" void kernel_launch(void* const* d_in, const int* in_sizes, int n_in,
                              void* d_out, int out_size, void* d_ws, size_t ws_size,
                              hipStream_t stream) {
    const float* x0    = (const float*)d_in[0];
    const int*   edge  = (const int*)d_in[1];
    const int*   batch = (const int*)d_in[2];
    const float* W     = (const float*)d_in[3];
    const float* bias  = (const float*)d_in[4];
    const float* lin_w = (const float*)d_in[5];
    const float* l1_w  = (const float*)d_in[6];
    const float* l1_b  = (const float*)d_in[7];
    const float* l2_w  = (const float*)d_in[8];
    const float* l2_b  = (const float*)d_in[9];
    float* out = (float*)d_out;

    int N = in_sizes[0] / H;
    int E = in_sizes[1] / 2;
    const int* src = edge;
    const int* dst = edge + E;

    size_t nh = (size_t)N * H;
    float* xA      = (float*)d_ws;
    float* xB      = xA + nh;
    float* pooled  = xB + nh;
    half_t* xhA    = (half_t*)(pooled + NGRAPH * 384);
    half_t* xhB    = xhA + nh;
    half_t* xaggh  = xhB + nh;
    half_t* WtT    = xaggh + nh;              // 128*256
    int* deg       = (int*)(WtT + 128 * 256);
    int* row_start = deg + N;                 // N+1
    int* cursor    = row_start + N + 1;
    int* csr_src   = cursor + N;              // E
    int* partials  = csr_src + E;             // 64
    int* blkoff    = partials + 64;           // 64

    prep_kernel<<<128, 256, 0, stream>>>(W, lin_w, WtT);
    cast_kernel<<<((int)(nh / 4) + 255) / 256, 256, 0, stream>>>(x0, xhA, (int)(nh / 4));

    hipMemsetAsync(deg, 0, (size_t)N * sizeof(int), stream);
    count_kernel<<<(E + 255) / 256, 256, 0, stream>>>(dst, deg, E);
    int nblk = (N + SCHUNK - 1) / SCHUNK;
    scan_part<<<nblk, 256, 0, stream>>>(deg, partials, N);
    scan_mid<<<1, 64, 0, stream>>>(partials, blkoff, nblk);
    scan_final<<<nblk, 256, 0, stream>>>(deg, blkoff, row_start, cursor, N, E);
    fill_kernel<<<(E + 255) / 256, 256, 0, stream>>>(src, dst, cursor, csr_src, E);

    const float* xcur = x0;
    const half_t* xcur_h = xhA;
    for (int it = 0; it < 5; ++it) {
        gather_agg<<<(N + 3) / 4, 256, 0, stream>>>(xcur_h, row_start, csr_src, xaggh, N);
        float* xnext = (it & 1) ? xB : xA;
        half_t* xnext_h = (it & 1) ? xhA : xhB;
        conv_mfma<<<(N + CROWS - 1) / CROWS, 256, 0, stream>>>(
            xcur, xcur_h, xaggh, WtT, bias, xnext, xnext_h, N, it < 4 ? 1 : 0);
        xcur = xnext;
        xcur_h = xnext_h;
    }

    pool_kernel<<<NGRAPH, 1024, 0, stream>>>(xcur, batch, pooled, N);
    mlp_kernel<<<NGRAPH, 256, 0, stream>>>(pooled, l1_w, l1_b, l2_w, l2_b, out);
}

// Round 7
// 444.491 us; speedup vs baseline: 1.0147x; 1.0147x over previous
//
#include <hip/hip_runtime.h>
#include <hip/hip_fp16.h>
#include <cmath>

#define H 128
#define GAMMA 0.1f
#define EPS 0.1f
#define NEG 0.01f
#define NGRAPH 256

typedef _Float16 half_t;
typedef _Float16 f16x8 __attribute__((ext_vector_type(8)));
typedef _Float16 f16x4 __attribute__((ext_vector_type(4)));
typedef float f32x4 __attribute__((ext_vector_type(4)));

__device__ __forceinline__ float fast_tanh(float v) {
    float e = __builtin_amdgcn_exp2f(v * 2.8853900817779268f);
    float r = __builtin_amdgcn_rcpf(e + 1.0f);
    return 1.0f - 2.0f * r;
}

// ---------------- precompute combined transposed weights, f16
__global__ void prep_kernel(const float* __restrict__ W, const float* __restrict__ lin_w,
                            half_t* __restrict__ WtT) {
    int idx = blockIdx.x * 256 + threadIdx.x;   // 32768 threads
    int j = idx >> 8, k = idx & 255;
    float v;
    if (k < H) v = W[j * H + k] - W[k * H + j] - (j == k ? GAMMA : 0.f);
    else       v = lin_w[j * H + (k - H)];
    WtT[j * 256 + k] = (half_t)v;
}

// ---------------- f32 -> f16 cast (x0 -> xh)
__global__ void cast_kernel(const float* __restrict__ x, half_t* __restrict__ xh, int n4) {
    int i = blockIdx.x * 256 + threadIdx.x;
    if (i < n4) {
        float4 v = *(const float4*)(x + (size_t)i * 4);
        half_t* o = xh + (size_t)i * 4;
        o[0] = (half_t)v.x; o[1] = (half_t)v.y; o[2] = (half_t)v.z; o[3] = (half_t)v.w;
    }
}

// ---------------- CSR build
__global__ void count_kernel(const int* __restrict__ dst, int* __restrict__ deg, int E) {
    int e = blockIdx.x * blockDim.x + threadIdx.x;
    if (e < E) atomicAdd(&deg[dst[e]], 1);
}

#define SCHUNK 2048
__global__ __launch_bounds__(256) void scan_part(const int* __restrict__ deg,
                                                 int* __restrict__ partials, int N) {
    __shared__ int red[256];
    int t = threadIdx.x, b = blockIdx.x;
    int base = b * SCHUNK + t * 8;
    int s = 0;
#pragma unroll
    for (int i = 0; i < 8; ++i) { int idx = base + i; if (idx < N) s += deg[idx]; }
    red[t] = s;
    __syncthreads();
    for (int off = 128; off > 0; off >>= 1) {
        if (t < off) red[t] += red[t + off];
        __syncthreads();
    }
    if (t == 0) partials[b] = red[0];
}

__global__ void scan_mid(const int* __restrict__ partials, int* __restrict__ blkoff, int nblk) {
    int lane = threadIdx.x;   // 64 threads
    int p = (lane < nblk) ? partials[lane] : 0;
    int v = p;
    for (int off = 1; off < 64; off <<= 1) {
        int u = __shfl_up(v, off);
        if (lane >= off) v += u;
    }
    if (lane < nblk) blkoff[lane] = v - p;
}

__global__ __launch_bounds__(256) void scan_final(const int* __restrict__ deg,
        const int* __restrict__ blkoff, int* __restrict__ row_start,
        int* __restrict__ cursor, int N, int E) {
    __shared__ int red[256];
    int t = threadIdx.x, b = blockIdx.x;
    int base = b * SCHUNK + t * 8;
    int v[8]; int s = 0;
#pragma unroll
    for (int i = 0; i < 8; ++i) { int idx = base + i; v[i] = (idx < N) ? deg[idx] : 0; s += v[i]; }
    red[t] = s;
    __syncthreads();
    for (int off = 1; off < 256; off <<= 1) {
        int u = (t >= off) ? red[t - off] : 0;
        __syncthreads();
        red[t] += u;
        __syncthreads();
    }
    int run = blkoff[b] + red[t] - s;
#pragma unroll
    for (int i = 0; i < 8; ++i) {
        int idx = base + i;
        if (idx < N) { row_start[idx] = run; cursor[idx] = run; run += v[i]; }
    }
    if (b == 0 && t == 0) row_start[N] = E;
}

__global__ void fill_kernel(const int* __restrict__ src, const int* __restrict__ dst,
                            int* __restrict__ cursor, int* __restrict__ csr_src, int E) {
    int e = blockIdx.x * blockDim.x + threadIdx.x;
    if (e < E) {
        int p = atomicAdd(&cursor[dst[e]], 1);
        csr_src[p] = src[e];
    }
}

// ---------------- gather aggregation: one wave per dst node.
// lane = 16*quad + li ; lane covers features [8*li, 8*li+8) (f16x8 = 16B).
// Main loop: 8 edges/step with TWO independent loads in flight (MLP!),
// then uniform 4-edge step, then masked uniform remainder.
// NOTE: ds_bpermute (__shfl) from an exec-inactive lane is UNDEFINED on CDNA —
// all shfl sites execute with the full wave active; only accumulates are masked.
__global__ __launch_bounds__(256) void gather_agg(const half_t* __restrict__ xh,
        const int* __restrict__ row_start, const int* __restrict__ csr_src,
        half_t* __restrict__ xaggh, int N) {
    int node = blockIdx.x * 4 + (threadIdx.x >> 6);
    if (node >= N) return;
    int lane = threadIdx.x & 63;
    int quad = lane >> 4, li = lane & 15;
    int begin = row_start[node], end = row_start[node + 1];
    float acc0[8] = {0.f}, acc1[8] = {0.f};
    for (int base = begin; base < end; base += 64) {
        int cnt = min(64, end - base);
        int myidx = (lane < cnt) ? csr_src[base + lane] : 0;
        int j = 0;
        for (; j + 7 < cnt; j += 8) {           // 2 independent loads in flight
            int s0 = __shfl(myidx, j + quad);
            int s1 = __shfl(myidx, j + 4 + quad);
            f16x8 v0 = *(const f16x8*)(xh + (size_t)s0 * H + li * 8);
            f16x8 v1 = *(const f16x8*)(xh + (size_t)s1 * H + li * 8);
#pragma unroll
            for (int k = 0; k < 8; ++k) acc0[k] += (float)v0[k];
#pragma unroll
            for (int k = 0; k < 8; ++k) acc1[k] += (float)v1[k];
        }
        int rem = cnt - j;                      // 0..7, wave-uniform
        if (rem >= 4) {                         // uniform 4-edge step
            int s0 = __shfl(myidx, j + quad);
            f16x8 v0 = *(const f16x8*)(xh + (size_t)s0 * H + li * 8);
#pragma unroll
            for (int k = 0; k < 8; ++k) acc0[k] += (float)v0[k];
            j += 4; rem -= 4;
        }
        if (rem > 0) {                          // masked remainder, all lanes shfl
            int sel = j + (quad < rem ? quad : 0);
            int s0 = __shfl(myidx, sel);
            f16x8 v0 = *(const f16x8*)(xh + (size_t)s0 * H + li * 8);
            if (quad < rem) {
#pragma unroll
                for (int k = 0; k < 8; ++k) acc1[k] += (float)v0[k];
            }
        }
    }
#pragma unroll
    for (int k = 0; k < 8; ++k) {
        float a = acc0[k] + acc1[k];
        a += __shfl_xor(a, 16);
        a += __shfl_xor(a, 32);
        acc0[k] = a;
    }
    if (quad == 0) {
        f16x8 o;
#pragma unroll
        for (int k = 0; k < 8; ++k) o[k] = (half_t)acc0[k];
        *(f16x8*)(xaggh + (size_t)node * H + li * 8) = o;
    }
}

// ---------------- fused conv+update via f16 MFMA
#define CROWS 128
#define BLDW 264   // 256 + 8 halfs pad
__global__ __launch_bounds__(256) void conv_mfma(
        const float* __restrict__ xin, const half_t* __restrict__ xh,
        const half_t* __restrict__ xaggh, const half_t* __restrict__ WtT,
        const float* __restrict__ bias,
        float* __restrict__ xout, half_t* __restrict__ xouth, int N, int write_h) {
    __shared__ __align__(16) half_t sB[128 * BLDW];
    int tid = threadIdx.x;
    for (int c = tid; c < 4096; c += 256) {
        int j = c >> 5, off = (c & 31) * 8;
        *(f16x8*)&sB[j * BLDW + off] = *(const f16x8*)(WtT + j * 256 + off);
    }
    __syncthreads();

    int wave = tid >> 6, lane = tid & 63;
    int q = lane >> 4, m = lane & 15;
    int rowbase = blockIdx.x * CROWS + wave * 32;

    f32x4 acc[2][8];
#pragma unroll
    for (int rt = 0; rt < 2; ++rt)
#pragma unroll
        for (int ct = 0; ct < 8; ++ct) acc[rt][ct] = (f32x4){0.f, 0.f, 0.f, 0.f};

#pragma unroll
    for (int s = 0; s < 8; ++s) {
        const half_t* srcA = (s < 4) ? xh : xaggh;
        int koff = (s & 3) * 32 + q * 8;
        f16x8 afrag[2];
#pragma unroll
        for (int rt = 0; rt < 2; ++rt) {
            int row = rowbase + rt * 16 + m;
            row = min(row, N - 1);
            afrag[rt] = *(const f16x8*)(srcA + (size_t)row * H + koff);
        }
#pragma unroll
        for (int ct = 0; ct < 8; ++ct) {
            f16x8 bfrag = *(const f16x8*)&sB[(ct * 16 + m) * BLDW + s * 32 + q * 8];
            acc[0][ct] = __builtin_amdgcn_mfma_f32_16x16x32_f16(afrag[0], bfrag, acc[0][ct], 0, 0, 0);
            acc[1][ct] = __builtin_amdgcn_mfma_f32_16x16x32_f16(afrag[1], bfrag, acc[1][ct], 0, 0, 0);
        }
    }

#pragma unroll
    for (int rt = 0; rt < 2; ++rt) {
#pragma unroll
        for (int r = 0; r < 4; ++r) {
            int row = rowbase + rt * 16 + q * 4 + r;
            if (row < N) {
#pragma unroll
                for (int ct = 0; ct < 8; ++ct) {
                    int col = ct * 16 + m;
                    float c = acc[rt][ct][r] + bias[col];
                    float o = xin[(size_t)row * H + col] + EPS * fast_tanh(c);
                    xout[(size_t)row * H + col] = o;
                    if (write_h) xouth[(size_t)row * H + col] = (half_t)o;
                }
            }
        }
    }
}

// ---------------- triple pooling: 1 block/graph, 1024 thr = 8 row-slots
__global__ __launch_bounds__(1024) void pool_kernel(const float* __restrict__ x,
        const int* __restrict__ batch, float* __restrict__ pooled, int N) {
    __shared__ float ssum[8][128];
    __shared__ float smax[8][128];
    int g = blockIdx.x, t = threadIdx.x;
    int feat = t & 127, slot = t >> 7;   // 8 slots
    int lo = 0, hi = N;
    while (lo < hi) { int mid = (lo + hi) >> 1; if (batch[mid] < g) lo = mid + 1; else hi = mid; }
    int start = lo;
    hi = N;
    while (lo < hi) { int mid = (lo + hi) >> 1; if (batch[mid] < g + 1) lo = mid + 1; else hi = mid; }
    int end = lo;
    float sum = 0.f, mx = -INFINITY;
    for (int n = start + slot; n < end; n += 8) {
        float v = x[(size_t)n * H + feat];
        sum += v;
        mx = fmaxf(mx, v);
    }
    ssum[slot][feat] = sum;
    smax[slot][feat] = mx;
    __syncthreads();
    if (t < 128) {
        float s = 0.f, m = -INFINITY;
#pragma unroll
        for (int k = 0; k < 8; ++k) { s += ssum[k][t]; m = fmaxf(m, smax[k][t]); }
        int cnt = end - start;
        pooled[g * 384 + t] = s;
        pooled[g * 384 + 128 + t] = (cnt > 0) ? m : 0.f;
        pooled[g * 384 + 256 + t] = s / (float)(cnt > 0 ? cnt : 1);
    }
}

// ---------------- final 2-layer MLP with leaky relu
__global__ void mlp_kernel(const float* __restrict__ pooled, const float* __restrict__ l1_w,
                           const float* __restrict__ l1_b, const float* __restrict__ l2_w,
                           const float* __restrict__ l2_b, float* __restrict__ out) {
    __shared__ __align__(16) float sp[384];
    __shared__ __align__(16) float sh[192];
    int g = blockIdx.x, tid = threadIdx.x;  // 256 threads
    for (int i = tid; i < 384; i += 256) sp[i] = pooled[g * 384 + i];
    __syncthreads();
    if (tid < 192) {
        float acc = l1_b[tid];
        const float* wr = l1_w + (size_t)tid * 384;
        for (int k = 0; k < 384; k += 4) {
            float4 w = *(const float4*)(wr + k);
            float4 p = *(const float4*)(sp + k);
            acc += w.x * p.x + w.y * p.y + w.z * p.z + w.w * p.w;
        }
        sh[tid] = acc > 0.f ? acc : NEG * acc;
    }
    __syncthreads();
    if (tid < 64) {
        float acc = l2_b[tid];
        const float* wr = l2_w + (size_t)tid * 192;
        for (int k = 0; k < 192; k += 4) {
            float4 w = *(const float4*)(wr + k);
            float4 p = *(const float4*)(sh + k);
            acc += w.x * p.x + w.y * p.y + w.z * p.z + w.w * p.w;
        }
        out[g * 64 + tid] = acc > 0.f ? acc : NEG * acc;
    }
}

extern "C" void kernel_launch(void* const* d_in, const int* in_sizes, int n_in,
                              void* d_out, int out_size, void* d_ws, size_t ws_size,
                              hipStream_t stream) {
    const float* x0    = (const float*)d_in[0];
    const int*   edge  = (const int*)d_in[1];
    const int*   batch = (const int*)d_in[2];
    const float* W     = (const float*)d_in[3];
    const float* bias  = (const float*)d_in[4];
    const float* lin_w = (const float*)d_in[5];
    const float* l1_w  = (const float*)d_in[6];
    const float* l1_b  = (const float*)d_in[7];
    const float* l2_w  = (const float*)d_in[8];
    const float* l2_b  = (const float*)d_in[9];
    float* out = (float*)d_out;

    int N = in_sizes[0] / H;
    int E = in_sizes[1] / 2;
    const int* src = edge;
    const int* dst = edge + E;

    size_t nh = (size_t)N * H;
    float* xA      = (float*)d_ws;
    float* xB      = xA + nh;
    float* pooled  = xB + nh;
    half_t* xhA    = (half_t*)(pooled + NGRAPH * 384);
    half_t* xhB    = xhA + nh;
    half_t* xaggh  = xhB + nh;
    half_t* WtT    = xaggh + nh;              // 128*256
    int* deg       = (int*)(WtT + 128 * 256);
    int* row_start = deg + N;                 // N+1
    int* cursor    = row_start + N + 1;
    int* csr_src   = cursor + N;              // E
    int* partials  = csr_src + E;             // 64
    int* blkoff    = partials + 64;           // 64

    prep_kernel<<<128, 256, 0, stream>>>(W, lin_w, WtT);
    cast_kernel<<<((int)(nh / 4) + 255) / 256, 256, 0, stream>>>(x0, xhA, (int)(nh / 4));

    hipMemsetAsync(deg, 0, (size_t)N * sizeof(int), stream);
    count_kernel<<<(E + 255) / 256, 256, 0, stream>>>(dst, deg, E);
    int nblk = (N + SCHUNK - 1) / SCHUNK;
    scan_part<<<nblk, 256, 0, stream>>>(deg, partials, N);
    scan_mid<<<1, 64, 0, stream>>>(partials, blkoff, nblk);
    scan_final<<<nblk, 256, 0, stream>>>(deg, blkoff, row_start, cursor, N, E);
    fill_kernel<<<(E + 255) / 256, 256, 0, stream>>>(src, dst, cursor, csr_src, E);

    const float* xcur = x0;
    const half_t* xcur_h = xhA;
    for (int it = 0; it < 5; ++it) {
        gather_agg<<<(N + 3) / 4, 256, 0, stream>>>(xcur_h, row_start, csr_src, xaggh, N);
        float* xnext = (it & 1) ? xB : xA;
        half_t* xnext_h = (it & 1) ? xhA : xhB;
        conv_mfma<<<(N + CROWS - 1) / CROWS, 256, 0, stream>>>(
            xcur, xcur_h, xaggh, WtT, bias, xnext, xnext_h, N, it < 4 ? 1 : 0);
        xcur = xnext;
        xcur_h = xnext_h;
    }

    pool_kernel<<<NGRAPH, 1024, 0, stream>>>(xcur, batch, pooled, N);
    mlp_kernel<<<NGRAPH, 256, 0, stream>>>(pooled, l1_w, l1_b, l2_w, l2_b, out);
}